// Round 1
// baseline (154.985 us; speedup 1.0000x reference)
//
#include <hip/hip_runtime.h>
#include <hip/hip_bf16.h>

#define TT 4
#define DD 384
#define HH0 160
#define HH1 128
#define HH2 96
#define NB 2048
#define NA 64
#define NN (NB*NA)

using bhalf8 = __attribute__((ext_vector_type(8))) __bf16;
using f32x4  = __attribute__((ext_vector_type(4))) float;

__device__ __forceinline__ unsigned short f2b(float f) {
  __hip_bfloat16 h = __float2bfloat16(f);
  union { __hip_bfloat16 h; unsigned short u; } c; c.h = h; return c.u;
}
__device__ __forceinline__ float b2f(unsigned short u) {
  union { unsigned int i; float f; } c; c.i = ((unsigned int)u) << 16; return c.f;
}
__device__ __forceinline__ float celu_f(float v) {
  return v > 0.f ? v : 0.1f * expm1f(v * 10.f);
}

// ---------------- small prep kernels ----------------

__global__ void k_zero(int* counts) {
  if (threadIdx.x < 12) counts[threadIdx.x] = 0;
}

__global__ void k_count(const int* __restrict__ species, int* __restrict__ counts,
                        float* __restrict__ out_sp) {
  __shared__ int lcnt[4];
  int tid = threadIdx.x;
  if (tid < 4) lcnt[tid] = 0;
  __syncthreads();
  int i = blockIdx.x * 256 + tid;
  int s = species[i];
  out_sp[i] = (float)s;
  atomicAdd(&lcnt[s], 1);
  __syncthreads();
  if (tid < 4) atomicAdd(&counts[tid], lcnt[tid]);
}

__global__ void k_scan(int* counts) {
  // counts[0..3], offsets at [4..7], cursors at [8..11]
  int o = 0;
  for (int t = 0; t < 4; ++t) { counts[4 + t] = o; counts[8 + t] = o; o += counts[t]; }
}

__global__ void k_scatter(const int* __restrict__ species, int* __restrict__ cursors,
                          int* __restrict__ sorted) {
  __shared__ int lcnt[4];
  __shared__ int lbase[4];
  int tid = threadIdx.x;
  if (tid < 4) lcnt[tid] = 0;
  __syncthreads();
  int i = blockIdx.x * 256 + tid;
  int s = species[i];
  int lpos = atomicAdd(&lcnt[s], 1);
  __syncthreads();
  if (tid < 4) lbase[tid] = atomicAdd(&cursors[tid], lcnt[tid]);
  __syncthreads();
  sorted[lbase[s] + lpos] = i;
}

// convert weights fp32 -> bf16, transposed to [type][neuron][k]
__global__ void k_wcvt(const float* __restrict__ W0, const float* __restrict__ W1,
                       const float* __restrict__ W2, const float* __restrict__ W3,
                       unsigned short* __restrict__ W0T, unsigned short* __restrict__ W1T,
                       unsigned short* __restrict__ W2T, unsigned short* __restrict__ W3B) {
  int id = blockIdx.x * 256 + threadIdx.x;
  if (id < 4*160*384) {
    int t = id / (160*384); int r = id % (160*384); int n = r / 384; int k = r % 384;
    W0T[id] = f2b(W0[t*384*160 + k*160 + n]);
  } else if ((id -= 4*160*384) < 4*128*160) {
    int t = id / (128*160); int r = id % (128*160); int n = r / 160; int k = r % 160;
    W1T[id] = f2b(W1[t*160*128 + k*128 + n]);
  } else if ((id -= 4*128*160) < 4*96*128) {
    int t = id / (96*128); int r = id % (96*128); int n = r / 128; int k = r % 128;
    W2T[id] = f2b(W2[t*128*96 + k*96 + n]);
  } else if ((id -= 4*96*128) < 4*96) {
    int t = id / 96; int k = id % 96;
    W3B[id] = f2b(W3[t*96 + k]);
  }
}

// ---------------- fused MFMA MLP ----------------
// LDS pool carve (bytes):
//   sH0:     0 .. 21504   ushort [64][168]
//   sXB: 21504 .. 30720   ushort [64][72]     (L0 only)
//   sW0: 30720 .. 53760   ushort [160][72]    (L0 only)
//   sH1: 30720 .. 48128   ushort [64][136]    (written after sW0 dead)
//   sW1: 48128 .. 58368   ushort [128][40]
//   sH2:     0 .. 13312   ushort [64][104]    (reuses sH0 after L1 done)
//   sW2: 48128 .. 55808   ushort [96][40]

__global__ __launch_bounds__(256, 2) void k_mlp(
    const float* __restrict__ aev, const int* __restrict__ sorted,
    const int* __restrict__ counts, const int* __restrict__ offsets,
    const unsigned short* __restrict__ W0T, const unsigned short* __restrict__ W1T,
    const unsigned short* __restrict__ W2T, const unsigned short* __restrict__ W3B,
    const float* __restrict__ b0, const float* __restrict__ b1,
    const float* __restrict__ b2, const float* __restrict__ b3,
    float* __restrict__ atom_out)
{
  int type = blockIdx.x;
  int tile = blockIdx.y;
  int cnt = counts[type];
  if (tile * 64 >= cnt) return;

  __shared__ uint4 smem4[58368 / 16];
  __shared__ int aidx[64];
  unsigned char* smem = (unsigned char*)smem4;
  unsigned short* sH0 = (unsigned short*)(smem + 0);
  unsigned short* sXB = (unsigned short*)(smem + 21504);
  unsigned short* sW0 = (unsigned short*)(smem + 30720);
  unsigned short* sH1 = (unsigned short*)(smem + 30720);
  unsigned short* sW1 = (unsigned short*)(smem + 48128);
  unsigned short* sH2 = (unsigned short*)(smem + 0);
  unsigned short* sW2 = (unsigned short*)(smem + 48128);

  int tid = threadIdx.x;
  int base = offsets[type] + tile * 64;
  int nvalid = min(64, cnt - tile * 64);
  if (tid < 64) aidx[tid] = sorted[base + min(tid, nvalid - 1)];
  __syncthreads();

  int lane = tid & 63;
  int w = tid >> 6;
  int wm = w & 1, wn = w >> 1;
  int l15 = lane & 15, lk = lane >> 4;

  int xrow = tid >> 2;
  int xq = tid & 3;
  int aidx_reg = aidx[xrow];

  const unsigned short* w0b = W0T + type * (160 * 384);
  const unsigned short* w1b = W1T + type * (128 * 160);
  const unsigned short* w2b = W2T + type * (96 * 128);

  // ---------- Layer 0: [64 x 384] @ [384 x 160] ----------
  f32x4 acc0[2][5];
  #pragma unroll
  for (int mt = 0; mt < 2; ++mt)
    #pragma unroll
    for (int nt = 0; nt < 5; ++nt) acc0[mt][nt] = f32x4{0.f, 0.f, 0.f, 0.f};

  for (int kc = 0; kc < 6; ++kc) {
    // stage X chunk: 64 atoms x 64 k, fp32 -> bf16
    {
      const float* src = aev + (size_t)aidx_reg * DD + kc * 64 + xq * 16;
      union { unsigned short us[16]; uint4 q[2]; } t;
      #pragma unroll
      for (int i = 0; i < 4; ++i) {
        float4 f = *(const float4*)(src + i * 4);
        t.us[i*4+0] = f2b(f.x); t.us[i*4+1] = f2b(f.y);
        t.us[i*4+2] = f2b(f.z); t.us[i*4+3] = f2b(f.w);
      }
      uint4* dst = (uint4*)&sXB[xrow * 72 + xq * 16];
      dst[0] = t.q[0]; dst[1] = t.q[1];
    }
    // stage W0^T chunk: [160 n][64 k]
    #pragma unroll
    for (int u2 = 0; u2 < 5; ++u2) {
      int fi = u2 * 256 + tid;
      int n = fi >> 3, ks = (fi & 7) * 8;
      *(uint4*)&sW0[n * 72 + ks] = *(const uint4*)&w0b[n * 384 + kc * 64 + ks];
    }
    __syncthreads();
    #pragma unroll
    for (int ks32 = 0; ks32 < 2; ++ks32) {
      int k0 = ks32 * 32 + lk * 8;
      bhalf8 af[2], bfv[5];
      #pragma unroll
      for (int mt = 0; mt < 2; ++mt)
        af[mt] = *(const bhalf8*)&sXB[(wm*32 + mt*16 + l15) * 72 + k0];
      #pragma unroll
      for (int nt = 0; nt < 5; ++nt)
        bfv[nt] = *(const bhalf8*)&sW0[(wn*80 + nt*16 + l15) * 72 + k0];
      #pragma unroll
      for (int mt = 0; mt < 2; ++mt)
        #pragma unroll
        for (int nt = 0; nt < 5; ++nt)
          acc0[mt][nt] = __builtin_amdgcn_mfma_f32_16x16x32_bf16(af[mt], bfv[nt], acc0[mt][nt], 0, 0, 0);
    }
    __syncthreads();
  }
  // epilogue L0 -> sH0
  #pragma unroll
  for (int mt = 0; mt < 2; ++mt)
    #pragma unroll
    for (int nt = 0; nt < 5; ++nt) {
      int col = wn*80 + nt*16 + l15;
      float bias = b0[type * HH0 + col];
      #pragma unroll
      for (int i = 0; i < 4; ++i) {
        int row = wm*32 + mt*16 + lk*4 + i;
        sH0[row * 168 + col] = f2b(celu_f(acc0[mt][nt][i] + bias));
      }
    }
  __syncthreads();

  // ---------- Layer 1: [64 x 160] @ [160 x 128] ----------
  f32x4 acc1[2][4];
  #pragma unroll
  for (int mt = 0; mt < 2; ++mt)
    #pragma unroll
    for (int nt = 0; nt < 4; ++nt) acc1[mt][nt] = f32x4{0.f, 0.f, 0.f, 0.f};

  for (int kc = 0; kc < 5; ++kc) {
    #pragma unroll
    for (int u2 = 0; u2 < 2; ++u2) {
      int fi = u2 * 256 + tid;   // < 512
      int n = fi >> 2, ks = (fi & 3) * 8;
      *(uint4*)&sW1[n * 40 + ks] = *(const uint4*)&w1b[n * 160 + kc * 32 + ks];
    }
    __syncthreads();
    bhalf8 af[2], bfv[4];
    #pragma unroll
    for (int mt = 0; mt < 2; ++mt)
      af[mt] = *(const bhalf8*)&sH0[(wm*32 + mt*16 + l15) * 168 + kc * 32 + lk * 8];
    #pragma unroll
    for (int nt = 0; nt < 4; ++nt)
      bfv[nt] = *(const bhalf8*)&sW1[(wn*64 + nt*16 + l15) * 40 + lk * 8];
    #pragma unroll
    for (int mt = 0; mt < 2; ++mt)
      #pragma unroll
      for (int nt = 0; nt < 4; ++nt)
        acc1[mt][nt] = __builtin_amdgcn_mfma_f32_16x16x32_bf16(af[mt], bfv[nt], acc1[mt][nt], 0, 0, 0);
    __syncthreads();
  }
  #pragma unroll
  for (int mt = 0; mt < 2; ++mt)
    #pragma unroll
    for (int nt = 0; nt < 4; ++nt) {
      int col = wn*64 + nt*16 + l15;
      float bias = b1[type * HH1 + col];
      #pragma unroll
      for (int i = 0; i < 4; ++i) {
        int row = wm*32 + mt*16 + lk*4 + i;
        sH1[row * 136 + col] = f2b(celu_f(acc1[mt][nt][i] + bias));
      }
    }
  __syncthreads();

  // ---------- Layer 2: [64 x 128] @ [128 x 96] ----------
  f32x4 acc2[2][3];
  #pragma unroll
  for (int mt = 0; mt < 2; ++mt)
    #pragma unroll
    for (int nt = 0; nt < 3; ++nt) acc2[mt][nt] = f32x4{0.f, 0.f, 0.f, 0.f};

  for (int kc = 0; kc < 4; ++kc) {
    #pragma unroll
    for (int u2 = 0; u2 < 2; ++u2) {
      int fi = u2 * 256 + tid;
      if (fi < 384) {
        int n = fi >> 2, ks = (fi & 3) * 8;
        *(uint4*)&sW2[n * 40 + ks] = *(const uint4*)&w2b[n * 128 + kc * 32 + ks];
      }
    }
    __syncthreads();
    bhalf8 af[2], bfv[3];
    #pragma unroll
    for (int mt = 0; mt < 2; ++mt)
      af[mt] = *(const bhalf8*)&sH1[(wm*32 + mt*16 + l15) * 136 + kc * 32 + lk * 8];
    #pragma unroll
    for (int nt = 0; nt < 3; ++nt)
      bfv[nt] = *(const bhalf8*)&sW2[(wn*48 + nt*16 + l15) * 40 + lk * 8];
    #pragma unroll
    for (int mt = 0; mt < 2; ++mt)
      #pragma unroll
      for (int nt = 0; nt < 3; ++nt)
        acc2[mt][nt] = __builtin_amdgcn_mfma_f32_16x16x32_bf16(af[mt], bfv[nt], acc2[mt][nt], 0, 0, 0);
    __syncthreads();
  }
  #pragma unroll
  for (int mt = 0; mt < 2; ++mt)
    #pragma unroll
    for (int nt = 0; nt < 3; ++nt) {
      int col = wn*48 + nt*16 + l15;
      float bias = b2[type * HH2 + col];
      #pragma unroll
      for (int i = 0; i < 4; ++i) {
        int row = wm*32 + mt*16 + lk*4 + i;
        sH2[row * 104 + col] = f2b(celu_f(acc2[mt][nt][i] + bias));
      }
    }
  __syncthreads();

  // ---------- Layer 3: [64 x 96] @ [96 x 1] ----------
  {
    int atom = tid >> 2;
    int ksub = (tid & 3) * 24;
    const unsigned short* w3 = W3B + type * 96;
    float s = 0.f;
    #pragma unroll
    for (int j = 0; j < 24; ++j)
      s += b2f(sH2[atom * 104 + ksub + j]) * b2f(w3[ksub + j]);
    s += __shfl_xor(s, 1);
    s += __shfl_xor(s, 2);
    if ((tid & 3) == 0 && atom < nvalid)
      atom_out[aidx[atom]] = s + b3[type];
  }
}

__global__ void k_reduce(const float* __restrict__ atom_out, float* __restrict__ out_e) {
  int mol = blockIdx.x;
  int lane = threadIdx.x;
  float v = atom_out[mol * 64 + lane];
  #pragma unroll
  for (int m = 32; m >= 1; m >>= 1) v += __shfl_xor(v, m);
  if (lane == 0) out_e[mol] = v;
}

// ---------------- launch ----------------

extern "C" void kernel_launch(void* const* d_in, const int* in_sizes, int n_in,
                              void* d_out, int out_size, void* d_ws, size_t ws_size,
                              hipStream_t stream) {
  const int*   species = (const int*)d_in[0];
  const float* aev = (const float*)d_in[1];
  const float* W0 = (const float*)d_in[2];
  const float* b0 = (const float*)d_in[3];
  const float* W1 = (const float*)d_in[4];
  const float* b1 = (const float*)d_in[5];
  const float* W2 = (const float*)d_in[6];
  const float* b2 = (const float*)d_in[7];
  const float* W3 = (const float*)d_in[8];
  const float* b3 = (const float*)d_in[9];
  float* out = (float*)d_out;

  unsigned char* ws = (unsigned char*)d_ws;
  int* counts = (int*)(ws + 0);                         // [4] + offsets[4] + cursors[4]
  int* sorted = (int*)(ws + 64);                        // int[NN]
  float* atom_out = (float*)(ws + 524352);              // float[NN]
  unsigned short* W0T = (unsigned short*)(ws + 1048640);
  unsigned short* W1T = (unsigned short*)(ws + 1540160);
  unsigned short* W2T = (unsigned short*)(ws + 1704000);
  unsigned short* W3B = (unsigned short*)(ws + 1802304);

  k_zero<<<1, 64, 0, stream>>>(counts);
  k_count<<<NN / 256, 256, 0, stream>>>(species, counts, out);
  k_scan<<<1, 1, 0, stream>>>(counts);
  k_scatter<<<NN / 256, 256, 0, stream>>>(species, counts + 8, sorted);
  k_wcvt<<<1474, 256, 0, stream>>>(W0, W1, W2, W3, W0T, W1T, W2T, W3B);
  k_mlp<<<dim3(4, 2048), 256, 0, stream>>>(aev, sorted, counts, counts + 4,
        W0T, W1T, W2T, W3B, b0, b1, b2, b3, atom_out);
  k_reduce<<<NB, 64, 0, stream>>>(atom_out, out + NN);
}

// Round 2
// 145.723 us; speedup vs baseline: 1.0636x; 1.0636x over previous
//
#include <hip/hip_runtime.h>
#include <hip/hip_bf16.h>

#define TT 4
#define DD 384
#define HH0 160
#define HH1 128
#define HH2 96
#define NB 2048
#define NA 64
#define NN (NB*NA)

using bhalf8 = __attribute__((ext_vector_type(8))) __bf16;
using f32x4  = __attribute__((ext_vector_type(4))) float;

__device__ __forceinline__ unsigned short f2b(float f) {
  __hip_bfloat16 h = __float2bfloat16(f);
  union { __hip_bfloat16 h; unsigned short u; } c; c.h = h; return c.u;
}
__device__ __forceinline__ float b2f(unsigned short u) {
  union { unsigned int i; float f; } c; c.i = ((unsigned int)u) << 16; return c.f;
}
__device__ __forceinline__ float celu_f(float v) {
  return v > 0.f ? v : 0.1f * expm1f(v * 10.f);
}

// ---------------- small prep kernels ----------------

__global__ void k_count(const int* __restrict__ species, int* __restrict__ counts,
                        float* __restrict__ out_sp) {
  __shared__ int lcnt[4];
  int tid = threadIdx.x;
  if (tid < 4) lcnt[tid] = 0;
  __syncthreads();
  int i = blockIdx.x * 256 + tid;
  int s = species[i];
  out_sp[i] = (float)s;
  atomicAdd(&lcnt[s], 1);
  __syncthreads();
  if (tid < 4) atomicAdd(&counts[tid], lcnt[tid]);
}

__global__ void k_scatter(const int* __restrict__ species, const int* __restrict__ counts,
                          int* __restrict__ cursors, int* __restrict__ sorted) {
  __shared__ int lcnt[4];
  __shared__ int lbase[4];
  int tid = threadIdx.x;
  if (tid < 4) lcnt[tid] = 0;
  __syncthreads();
  int i = blockIdx.x * 256 + tid;
  int s = species[i];
  int lpos = atomicAdd(&lcnt[s], 1);
  __syncthreads();
  if (tid < 4) {
    int offs = 0;
    #pragma unroll
    for (int t = 0; t < 4; ++t) if (t < tid) offs += counts[t];
    lbase[tid] = offs + atomicAdd(&cursors[tid], lcnt[tid]);
  }
  __syncthreads();
  sorted[lbase[s] + lpos] = i;
}

// convert weights fp32 -> bf16, transposed to [type][neuron][k]
__global__ void k_wcvt(const float* __restrict__ W0, const float* __restrict__ W1,
                       const float* __restrict__ W2, const float* __restrict__ W3,
                       unsigned short* __restrict__ W0T, unsigned short* __restrict__ W1T,
                       unsigned short* __restrict__ W2T, unsigned short* __restrict__ W3B) {
  int id = blockIdx.x * 256 + threadIdx.x;
  if (id < 4*160*384) {
    int t = id / (160*384); int r = id % (160*384); int n = r / 384; int k = r % 384;
    W0T[id] = f2b(W0[t*384*160 + k*160 + n]);
  } else if ((id -= 4*160*384) < 4*128*160) {
    int t = id / (128*160); int r = id % (128*160); int n = r / 160; int k = r % 160;
    W1T[id] = f2b(W1[t*160*128 + k*128 + n]);
  } else if ((id -= 4*128*160) < 4*96*128) {
    int t = id / (96*128); int r = id % (96*128); int n = r / 128; int k = r % 128;
    W2T[id] = f2b(W2[t*128*96 + k*96 + n]);
  } else if ((id -= 4*96*128) < 4*96) {
    int t = id / 96; int k = id % 96;
    W3B[id] = f2b(W3[t*96 + k]);
  }
}

// ---------------- fused MFMA MLP ----------------
// LDS carve (bytes), total 39936 + aidx:
//   region A:     0 .. 21504  sH0 ushort[64][168];  sH2 ushort[64][104] overlays at 0
//   region B: 21504 .. 39936  sXB 2 x ushort[64][72] (dbuf, L0); sH1 ushort[64][136] overlays
// Weights are NOT staged in LDS: B-fragments load global->VGPR (L2-resident, 753 KB total).

__global__ __launch_bounds__(256, 4) void k_mlp(
    const float* __restrict__ aev, const int* __restrict__ sorted,
    const int* __restrict__ counts,
    const unsigned short* __restrict__ W0T, const unsigned short* __restrict__ W1T,
    const unsigned short* __restrict__ W2T, const unsigned short* __restrict__ W3B,
    const float* __restrict__ b0, const float* __restrict__ b1,
    const float* __restrict__ b2, const float* __restrict__ b3,
    float* __restrict__ atom_out)
{
  int type = blockIdx.x;
  int tile = blockIdx.y;
  int c0 = counts[0], c1 = counts[1], c2 = counts[2], c3 = counts[3];
  int cnt = (type == 0) ? c0 : (type == 1) ? c1 : (type == 2) ? c2 : c3;
  if (tile * 64 >= cnt) return;
  int off = 0;
  if (type > 0) off += c0;
  if (type > 1) off += c1;
  if (type > 2) off += c2;

  __shared__ uint4 smem4[39936 / 16];
  __shared__ int aidx[64];
  unsigned char* smem = (unsigned char*)smem4;
  unsigned short* sH0 = (unsigned short*)(smem + 0);       // [64][168]
  unsigned short* sH2 = (unsigned short*)(smem + 0);       // [64][104]
  unsigned short* sXB = (unsigned short*)(smem + 21504);   // [2][64][72]
  unsigned short* sH1 = (unsigned short*)(smem + 21504);   // [64][136]

  int tid = threadIdx.x;
  int base = off + tile * 64;
  int nvalid = min(64, cnt - tile * 64);
  if (tid < 64) aidx[tid] = sorted[base + min(tid, nvalid - 1)];
  __syncthreads();

  int lane = tid & 63;
  int w = tid >> 6;
  int wm = w & 1, wn = w >> 1;
  int l15 = lane & 15, lk = lane >> 4;

  int xrow = tid >> 2;          // atom 0..63
  int xq = tid & 3;             // 16-float chunk within 64-k slab
  int aidx_reg = aidx[xrow];
  const float* xsrc = aev + (size_t)aidx_reg * DD + xq * 16;

  const unsigned short* w0b = W0T + type * (160 * 384);
  const unsigned short* w1b = W1T + type * (128 * 160);
  const unsigned short* w2b = W2T + type * (96 * 128);

  // per-lane B base pointers (row = neuron, contiguous k)
  const unsigned short* b0p = w0b + (size_t)(wn * 80 + l15) * 384 + lk * 8;
  const unsigned short* b1p = w1b + (size_t)(wn * 64 + l15) * 160 + lk * 8;
  const unsigned short* b2p = w2b + (size_t)(wn * 48 + l15) * 128 + lk * 8;

  // ---------- Layer 0: [64 x 384] @ [384 x 160], K-chunks of 64, dbuf ----------
  f32x4 acc0[2][5];
  #pragma unroll
  for (int mt = 0; mt < 2; ++mt)
    #pragma unroll
    for (int nt = 0; nt < 5; ++nt) acc0[mt][nt] = f32x4{0.f, 0.f, 0.f, 0.f};

  // prestage chunk 0 into buf 0
  {
    const float* src = xsrc;
    union { unsigned short us[16]; uint4 q[2]; } t;
    #pragma unroll
    for (int i = 0; i < 4; ++i) {
      float4 f = *(const float4*)(src + i * 4);
      t.us[i*4+0] = f2b(f.x); t.us[i*4+1] = f2b(f.y);
      t.us[i*4+2] = f2b(f.z); t.us[i*4+3] = f2b(f.w);
    }
    uint4* dst = (uint4*)&sXB[xrow * 72 + xq * 16];
    dst[0] = t.q[0]; dst[1] = t.q[1];
  }
  __syncthreads();

  for (int kc = 0; kc < 6; ++kc) {
    // prefetch next chunk into other buffer (no barrier needed before writes:
    // that buffer's readers finished at the previous iteration's barrier)
    if (kc < 5) {
      const float* src = xsrc + (kc + 1) * 64;
      union { unsigned short us[16]; uint4 q[2]; } t;
      #pragma unroll
      for (int i = 0; i < 4; ++i) {
        float4 f = *(const float4*)(src + i * 4);
        t.us[i*4+0] = f2b(f.x); t.us[i*4+1] = f2b(f.y);
        t.us[i*4+2] = f2b(f.z); t.us[i*4+3] = f2b(f.w);
      }
      uint4* dst = (uint4*)&sXB[((kc + 1) & 1) * 4608 + xrow * 72 + xq * 16];
      dst[0] = t.q[0]; dst[1] = t.q[1];
    }
    const unsigned short* bufc = sXB + (kc & 1) * 4608;
    #pragma unroll
    for (int ks = 0; ks < 2; ++ks) {
      int k0 = ks * 32 + lk * 8;
      bhalf8 af[2], bfv[5];
      #pragma unroll
      for (int mt = 0; mt < 2; ++mt)
        af[mt] = *(const bhalf8*)&bufc[(wm*32 + mt*16 + l15) * 72 + k0];
      #pragma unroll
      for (int nt = 0; nt < 5; ++nt)
        bfv[nt] = *(const bhalf8*)&b0p[nt * 16 * 384 + kc * 64 + ks * 32];
      #pragma unroll
      for (int mt = 0; mt < 2; ++mt)
        #pragma unroll
        for (int nt = 0; nt < 5; ++nt)
          acc0[mt][nt] = __builtin_amdgcn_mfma_f32_16x16x32_bf16(af[mt], bfv[nt], acc0[mt][nt], 0, 0, 0);
    }
    __syncthreads();
  }

  // epilogue L0 -> sH0
  #pragma unroll
  for (int mt = 0; mt < 2; ++mt)
    #pragma unroll
    for (int nt = 0; nt < 5; ++nt) {
      int col = wn*80 + nt*16 + l15;
      float bias = b0[type * HH0 + col];
      #pragma unroll
      for (int i = 0; i < 4; ++i) {
        int row = wm*32 + mt*16 + lk*4 + i;
        sH0[row * 168 + col] = f2b(celu_f(acc0[mt][nt][i] + bias));
      }
    }
  __syncthreads();

  // ---------- Layer 1: [64 x 160] @ [160 x 128], no barriers inside ----------
  f32x4 acc1[2][4];
  #pragma unroll
  for (int mt = 0; mt < 2; ++mt)
    #pragma unroll
    for (int nt = 0; nt < 4; ++nt) acc1[mt][nt] = f32x4{0.f, 0.f, 0.f, 0.f};

  #pragma unroll
  for (int kc = 0; kc < 5; ++kc) {
    bhalf8 af[2], bfv[4];
    #pragma unroll
    for (int mt = 0; mt < 2; ++mt)
      af[mt] = *(const bhalf8*)&sH0[(wm*32 + mt*16 + l15) * 168 + kc * 32 + lk * 8];
    #pragma unroll
    for (int nt = 0; nt < 4; ++nt)
      bfv[nt] = *(const bhalf8*)&b1p[nt * 16 * 160 + kc * 32];
    #pragma unroll
    for (int mt = 0; mt < 2; ++mt)
      #pragma unroll
      for (int nt = 0; nt < 4; ++nt)
        acc1[mt][nt] = __builtin_amdgcn_mfma_f32_16x16x32_bf16(af[mt], bfv[nt], acc1[mt][nt], 0, 0, 0);
  }
  // epilogue L1 -> sH1 (overlays sXB; safe: all waves passed post-L0 barrier)
  #pragma unroll
  for (int mt = 0; mt < 2; ++mt)
    #pragma unroll
    for (int nt = 0; nt < 4; ++nt) {
      int col = wn*64 + nt*16 + l15;
      float bias = b1[type * HH1 + col];
      #pragma unroll
      for (int i = 0; i < 4; ++i) {
        int row = wm*32 + mt*16 + lk*4 + i;
        sH1[row * 136 + col] = f2b(celu_f(acc1[mt][nt][i] + bias));
      }
    }
  __syncthreads();

  // ---------- Layer 2: [64 x 128] @ [128 x 96] ----------
  f32x4 acc2[2][3];
  #pragma unroll
  for (int mt = 0; mt < 2; ++mt)
    #pragma unroll
    for (int nt = 0; nt < 3; ++nt) acc2[mt][nt] = f32x4{0.f, 0.f, 0.f, 0.f};

  #pragma unroll
  for (int kc = 0; kc < 4; ++kc) {
    bhalf8 af[2], bfv[3];
    #pragma unroll
    for (int mt = 0; mt < 2; ++mt)
      af[mt] = *(const bhalf8*)&sH1[(wm*32 + mt*16 + l15) * 136 + kc * 32 + lk * 8];
    #pragma unroll
    for (int nt = 0; nt < 3; ++nt)
      bfv[nt] = *(const bhalf8*)&b2p[nt * 16 * 128 + kc * 32];
    #pragma unroll
    for (int mt = 0; mt < 2; ++mt)
      #pragma unroll
      for (int nt = 0; nt < 3; ++nt)
        acc2[mt][nt] = __builtin_amdgcn_mfma_f32_16x16x32_bf16(af[mt], bfv[nt], acc2[mt][nt], 0, 0, 0);
  }
  // epilogue L2 -> sH2 (overlays sH0; safe: all waves passed post-L1 barrier)
  #pragma unroll
  for (int mt = 0; mt < 2; ++mt)
    #pragma unroll
    for (int nt = 0; nt < 3; ++nt) {
      int col = wn*48 + nt*16 + l15;
      float bias = b2[type * HH2 + col];
      #pragma unroll
      for (int i = 0; i < 4; ++i) {
        int row = wm*32 + mt*16 + lk*4 + i;
        sH2[row * 104 + col] = f2b(celu_f(acc2[mt][nt][i] + bias));
      }
    }
  __syncthreads();

  // ---------- Layer 3: [64 x 96] @ [96 x 1], vectorized b128 reads ----------
  {
    int atom = tid >> 2;
    int q = tid & 3;
    const unsigned short* w3 = W3B + type * 96 + q * 24;
    const unsigned short* hrow = sH2 + atom * 104 + q * 24;
    float s = 0.f;
    #pragma unroll
    for (int i = 0; i < 3; ++i) {
      union { bhalf8 v; unsigned short u[8]; } hu, wu;
      hu.v = *(const bhalf8*)&hrow[i * 8];
      wu.v = *(const bhalf8*)&w3[i * 8];
      #pragma unroll
      for (int j = 0; j < 8; ++j)
        s += b2f(hu.u[j]) * b2f(wu.u[j]);
    }
    s += __shfl_xor(s, 1);
    s += __shfl_xor(s, 2);
    if (q == 0 && atom < nvalid)
      atom_out[aidx[atom]] = s + b3[type];
  }
}

__global__ void k_reduce(const float* __restrict__ atom_out, float* __restrict__ out_e) {
  int mol = blockIdx.x;
  int lane = threadIdx.x;
  float v = atom_out[mol * 64 + lane];
  #pragma unroll
  for (int m = 32; m >= 1; m >>= 1) v += __shfl_xor(v, m);
  if (lane == 0) out_e[mol] = v;
}

// ---------------- launch ----------------

extern "C" void kernel_launch(void* const* d_in, const int* in_sizes, int n_in,
                              void* d_out, int out_size, void* d_ws, size_t ws_size,
                              hipStream_t stream) {
  const int*   species = (const int*)d_in[0];
  const float* aev = (const float*)d_in[1];
  const float* W0 = (const float*)d_in[2];
  const float* b0 = (const float*)d_in[3];
  const float* W1 = (const float*)d_in[4];
  const float* b1 = (const float*)d_in[5];
  const float* W2 = (const float*)d_in[6];
  const float* b2 = (const float*)d_in[7];
  const float* W3 = (const float*)d_in[8];
  const float* b3 = (const float*)d_in[9];
  float* out = (float*)d_out;

  unsigned char* ws = (unsigned char*)d_ws;
  int* counts = (int*)(ws + 0);                         // [4] counts + [4] unused + [4] cursors
  int* sorted = (int*)(ws + 64);                        // int[NN]
  float* atom_out = (float*)(ws + 524352);              // float[NN]
  unsigned short* W0T = (unsigned short*)(ws + 1048640);
  unsigned short* W1T = (unsigned short*)(ws + 1540160);
  unsigned short* W2T = (unsigned short*)(ws + 1704000);
  unsigned short* W3B = (unsigned short*)(ws + 1802304);

  hipMemsetAsync(counts, 0, 48, stream);
  k_count<<<NN / 256, 256, 0, stream>>>(species, counts, out);
  k_scatter<<<NN / 256, 256, 0, stream>>>(species, counts, counts + 8, sorted);
  k_wcvt<<<1474, 256, 0, stream>>>(W0, W1, W2, W3, W0T, W1T, W2T, W3B);
  k_mlp<<<dim3(4, 2048), 256, 0, stream>>>(aev, sorted, counts,
        W0T, W1T, W2T, W3B, b0, b1, b2, b3, atom_out);
  k_reduce<<<NB, 64, 0, stream>>>(atom_out, out + NN);
}